// Round 1
// baseline (1387.704 us; speedup 1.0000x reference)
//
#include <hip/hip_runtime.h>
#include <math.h>

#define BB 8
#define SS 2048
#define DD 512
#define HH 8
#define MM (BB*SS)   // 16384

// ---------------- prep kernels (tiny, once per launch) ----------------
__global__ void prep_wcat(const float* __restrict__ Wr, const float* __restrict__ Wi,
                          float* __restrict__ WcatT){
  int id = blockIdx.x*blockDim.x + threadIdx.x;           // 1024*512
  if (id >= 1024*512) return;
  int k = id >> 9, n = id & 511;                          // WcatT[k][n]
  if (k < 512) WcatT[id] = Wr[n*512 + k] + Wi[n*512 + k];
  else         WcatT[id] = Wr[n*512 + (k-512)] - Wi[n*512 + (k-512)];
}
__global__ void prep_qkvT(const float* __restrict__ Wq, float* __restrict__ WqkvT){
  int id = blockIdx.x*blockDim.x + threadIdx.x;           // 512*1536
  if (id >= 512*1536) return;
  int k = id / 1536, n = id % 1536;                       // WqkvT[k][n] = Wq[n][k]
  WqkvT[id] = Wq[n*512 + k];
}
__global__ void prep_woT(const float* __restrict__ Wor, const float* __restrict__ Woi,
                         float* __restrict__ WoT){
  int id = blockIdx.x*blockDim.x + threadIdx.x;           // 512*1024
  if (id >= 512*1024) return;
  int k = id >> 10, n = id & 1023;                        // WoT[k][n]
  WoT[id] = (n < 512) ? Wor[n*512 + k] : Woi[(n-512)*512 + k];
}
__global__ void prep_misc(const float* __restrict__ br, const float* __restrict__ bi,
                          const float* __restrict__ la, float* __restrict__ bc,
                          float* __restrict__ alph, float* __restrict__ pw){
  int t = threadIdx.x;
  if (t < 512) bc[t] = br[t] + bi[t];
  if (t < 8){
    float a = 1.0f/(1.0f + expf(-la[t]));
    alph[t] = a;
    float om = 1.0f - a;
    float p = 1.0f;
    pw[t*33] = 1.0f;
    for (int i=1;i<33;i++){ p *= om; pw[t*33+i] = p; }
  }
}

// ---------------- phase 1: elementwise h-recurrence ----------------
// hr2[t] = cos(theta), hi2[t] = sin(theta), theta = (hr+hi)/wl + 2*b_t + 2*tphi
// Writes X[M][1024]: cols 0..511 = hr2, cols 512..1023 = hi2 (row r = b*S+t)
__global__ __launch_bounds__(256) void scan_h(const float* __restrict__ w,
                                              const float* __restrict__ bb,
                                              float* __restrict__ X){
  const int gid = blockIdx.x*256 + threadIdx.x;   // 4096 = B*D
  const int b = gid >> 9;
  const int d = gid & 511;
  const float PHI_F    = 1.61803398874989484820f;
  const float TWO_PI_F = 6.28318530717958647693f;
  const float* wp = w  + (size_t)b*SS*DD + d;
  const float* bp = bb + (size_t)b*SS*DD + d;
  float* xp = X + (size_t)b*SS*1024 + d;
  float hr = 0.f, hi = 0.f;
  const int U = 16;
  float wv[U], bv[U], wn[U], bn[U];
  #pragma unroll
  for (int i=0;i<U;i++){ wv[i] = wp[(size_t)i*DD]; bv[i] = bp[(size_t)i*DD]; }
  for (int c = 0; c < SS/U; ++c){
    if (c+1 < SS/U){
      const size_t base = (size_t)(c+1)*U;
      #pragma unroll
      for (int i=0;i<U;i++){ wn[i] = wp[(base+i)*DD]; bn[i] = bp[(base+i)*DD]; }
    }
    #pragma unroll
    for (int i=0;i<U;i++){
      int t = c*U + i;
      float tphi = fmodf((float)t * PHI_F, TWO_PI_F);
      float rwl = 1.0f/(1.0f + fabsf(wv[i]));
      float theta = (hr + hi)*rwl + 2.0f*bv[i] + 2.0f*tphi;
      float sn = __sinf(theta);
      float cs = __cosf(theta);
      hr = cs; hi = sn;
      float* row = xp + (size_t)t*1024;
      row[0]   = cs;
      row[512] = sn;
    }
    #pragma unroll
    for (int i=0;i<U;i++){ wv[i]=wn[i]; bv[i]=bn[i]; }
  }
}

// ---------------- generic fp32 GEMM: C[M x N] = A[M x K] @ Wt[K x N] ----------------
// 128x128 tile, BK=16, 256 threads, 8x8 per thread.
// EPI==0: store to C0 (row stride N). EPI==1: cols<512 -> C0, else -> C1 (row stride 512 each).
__global__ __launch_bounds__(256) void gemm_f32(const float* __restrict__ A,
                                                const float* __restrict__ Wt,
                                                float* __restrict__ C0,
                                                float* __restrict__ C1,
                                                int N, int K, int EPI){
  __shared__ float As[16][128];   // [k][m]
  __shared__ float Bs[16][128];   // [k][n]
  const int tid = threadIdx.x;
  const int m0 = blockIdx.y * 128;
  const int n0 = blockIdx.x * 128;
  const int ty = tid >> 4, tx = tid & 15;
  float acc[8][8];
  #pragma unroll
  for (int i=0;i<8;i++)
    #pragma unroll
    for (int j=0;j<8;j++) acc[i][j] = 0.f;

  const int ra = tid >> 2;          // 0..63
  const int kc = (tid & 3) * 4;     // 0,4,8,12
  const int kb = tid >> 5;          // 0..7
  const int nc = (tid & 31) * 4;    // 0..124

  for (int k0 = 0; k0 < K; k0 += 16){
    float4 a0 = *(const float4*)(A + (size_t)(m0 + ra)      * K + k0 + kc);
    float4 a1 = *(const float4*)(A + (size_t)(m0 + ra + 64) * K + k0 + kc);
    float4 b0 = *(const float4*)(Wt + (size_t)(k0 + kb)     * N + n0 + nc);
    float4 b1 = *(const float4*)(Wt + (size_t)(k0 + kb + 8) * N + n0 + nc);
    As[kc+0][ra] = a0.x; As[kc+1][ra] = a0.y; As[kc+2][ra] = a0.z; As[kc+3][ra] = a0.w;
    As[kc+0][ra+64] = a1.x; As[kc+1][ra+64] = a1.y; As[kc+2][ra+64] = a1.z; As[kc+3][ra+64] = a1.w;
    *(float4*)&Bs[kb][nc]   = b0;
    *(float4*)&Bs[kb+8][nc] = b1;
    __syncthreads();
    #pragma unroll
    for (int k=0;k<16;k++){
      float4 xa0 = *(float4*)&As[k][ty*8];
      float4 xa1 = *(float4*)&As[k][ty*8+4];
      float4 xb0 = *(float4*)&Bs[k][tx*8];
      float4 xb1 = *(float4*)&Bs[k][tx*8+4];
      float av[8] = {xa0.x,xa0.y,xa0.z,xa0.w,xa1.x,xa1.y,xa1.z,xa1.w};
      float bvv[8] = {xb0.x,xb0.y,xb0.z,xb0.w,xb1.x,xb1.y,xb1.z,xb1.w};
      #pragma unroll
      for (int i=0;i<8;i++)
        #pragma unroll
        for (int j=0;j<8;j++) acc[i][j] = fmaf(av[i], bvv[j], acc[i][j]);
    }
    __syncthreads();
  }
  #pragma unroll
  for (int i=0;i<8;i++){
    int r = m0 + ty*8 + i;
    float4 c0 = make_float4(acc[i][0],acc[i][1],acc[i][2],acc[i][3]);
    float4 c1 = make_float4(acc[i][4],acc[i][5],acc[i][6],acc[i][7]);
    if (EPI == 0){
      *(float4*)(C0 + (size_t)r*N + n0 + tx*8)     = c0;
      *(float4*)(C0 + (size_t)r*N + n0 + tx*8 + 4) = c1;
    } else {
      int col = n0 + tx*8;   // tile never straddles col 512 (128-aligned)
      float* dst = (col < 512) ? (C0 + (size_t)r*512 + col)
                               : (C1 + (size_t)r*512 + (col - 512));
      *(float4*)dst     = c0;
      *(float4*)(dst+4) = c1;
    }
  }
}

// ---------------- LayerNorm, in place on y: xc = LN(y + bc)*g + b ----------------
__global__ __launch_bounds__(256) void ln_kernel(float* __restrict__ y,
                                                 const float* __restrict__ bc,
                                                 const float* __restrict__ g,
                                                 const float* __restrict__ bb){
  const int row  = blockIdx.x*4 + (threadIdx.x >> 6);
  const int lane = threadIdx.x & 63;
  float* yr = y + (size_t)row*512;
  float4 v0 = ((const float4*)yr)[lane];
  float4 v1 = ((const float4*)yr)[lane+64];
  float4 c0 = ((const float4*)bc)[lane];
  float4 c1 = ((const float4*)bc)[lane+64];
  v0.x+=c0.x; v0.y+=c0.y; v0.z+=c0.z; v0.w+=c0.w;
  v1.x+=c1.x; v1.y+=c1.y; v1.z+=c1.z; v1.w+=c1.w;
  float s  = v0.x+v0.y+v0.z+v0.w + v1.x+v1.y+v1.z+v1.w;
  float s2 = v0.x*v0.x+v0.y*v0.y+v0.z*v0.z+v0.w*v0.w
           + v1.x*v1.x+v1.y*v1.y+v1.z*v1.z+v1.w*v1.w;
  #pragma unroll
  for (int off=32; off>0; off>>=1){ s += __shfl_xor(s, off); s2 += __shfl_xor(s2, off); }
  float mean = s * (1.0f/512.0f);
  float var  = s2 * (1.0f/512.0f) - mean*mean;
  float rstd = rsqrtf(var + 1e-5f);
  float4 g0 = ((const float4*)g)[lane],  g1 = ((const float4*)g)[lane+64];
  float4 b0 = ((const float4*)bb)[lane], b1 = ((const float4*)bb)[lane+64];
  v0.x = (v0.x-mean)*rstd*g0.x + b0.x;
  v0.y = (v0.y-mean)*rstd*g0.y + b0.y;
  v0.z = (v0.z-mean)*rstd*g0.z + b0.z;
  v0.w = (v0.w-mean)*rstd*g0.w + b0.w;
  v1.x = (v1.x-mean)*rstd*g1.x + b1.x;
  v1.y = (v1.y-mean)*rstd*g1.y + b1.y;
  v1.z = (v1.z-mean)*rstd*g1.z + b1.z;
  v1.w = (v1.w-mean)*rstd*g1.w + b1.w;
  ((float4*)yr)[lane]    = v0;
  ((float4*)yr)[lane+64] = v1;
}

// ---------------- vs EMA: chunked parallel scan ----------------
// Chunk local scans (init 0) + chunk-end values E[c][b*512+d]
__global__ __launch_bounds__(256) void vscan_local(const float* __restrict__ qkv,
                                                   const float* __restrict__ alph,
                                                   float* __restrict__ L,
                                                   float* __restrict__ E){
  const int gid = blockIdx.x*256 + threadIdx.x;   // 64 chunks * 4096 elements
  const int c = gid >> 12;
  const int e = gid & 4095;
  const int b = e >> 9, d = e & 511;
  const float a  = alph[d >> 6];
  const float om = 1.0f - a;
  const int t0 = c*32;
  const float* vp = qkv + ((size_t)(b*SS + t0))*1536 + 1024 + d;
  float* lp = L + ((size_t)(b*SS + t0))*512 + d;
  float vs = 0.f;
  #pragma unroll 4
  for (int i=0;i<32;i++){
    float v = vp[(size_t)i*1536];
    vs = a*v + om*vs;
    lp[(size_t)i*512] = vs;
  }
  E[c*4096 + e] = vs;
}
// Sequential over 64 chunks per element: carry BEFORE chunk c
__global__ void vscan_carry(const float* __restrict__ E, const float* __restrict__ alph,
                            const float* __restrict__ pw, float* __restrict__ Cp){
  const int gid = blockIdx.x*blockDim.x + threadIdx.x;  // 4096
  if (gid >= 4096) return;
  const int d = gid & 511;
  const float P = pw[(d>>6)*33 + 32];   // (1-a)^32
  float carry = 0.f;
  for (int c=0;c<64;c++){
    Cp[c*4096 + gid] = carry;
    carry = E[c*4096 + gid] + P*carry;
  }
}
// gate + vs fix-up + retr  (one wave == one head: Dh=64)
__global__ __launch_bounds__(256) void retr_kernel(const float* __restrict__ qkv,
                                                   const float* __restrict__ L,
                                                   const float* __restrict__ Cp,
                                                   const float* __restrict__ pw,
                                                   float* __restrict__ retr){
  const int gid = blockIdx.x*256 + threadIdx.x;   // M*512
  const int r = gid >> 9, d = gid & 511;
  const int b = r >> 11, t = r & 2047;
  float q  = qkv[(size_t)r*1536 + d];
  float kk = qkv[(size_t)r*1536 + 512 + d];
  float qk = q*kk;
  #pragma unroll
  for (int off=32; off>0; off>>=1) qk += __shfl_xor(qk, off);
  float gate = 1.0f/(1.0f + __expf(-qk*0.125f));
  int h = d >> 6, c = t >> 5, i = t & 31;
  float vs = L[gid] + pw[h*33 + i + 1] * Cp[c*4096 + b*512 + d];
  retr[gid] = gate * vs;
}

extern "C" void kernel_launch(void* const* d_in, const int* in_sizes, int n_in,
                              void* d_out, int out_size, void* d_ws, size_t ws_size,
                              hipStream_t stream) {
  const float* w    = (const float*)d_in[0];
  const float* b    = (const float*)d_in[1];
  const float* ipWr = (const float*)d_in[2];
  const float* ipWi = (const float*)d_in[3];
  const float* ipbr = (const float*)d_in[4];
  const float* ipbi = (const float*)d_in[5];
  const float* lng  = (const float*)d_in[6];
  const float* lnb  = (const float*)d_in[7];
  const float* Wqkv = (const float*)d_in[8];
  const float* la   = (const float*)d_in[9];
  const float* opWr = (const float*)d_in[10];
  const float* opWi = (const float*)d_in[11];
  float* out0 = (float*)d_out;                    // (B,S,D) real part
  float* out1 = out0 + (size_t)MM*DD;             // imag part

  float* fw    = (float*)d_ws;
  float* WcatT = fw;                    // 1024*512
  float* WqkvT = fw + 524288;           // 512*1536
  float* WoT   = fw + 1310720;          // 512*1024
  float* bc    = fw + 1835008;          // 512
  float* alph  = fw + 1835520;          // 8
  float* pw    = fw + 1835648;          // 8*33
  float* E     = fw + 1836032;          // 64*4096
  float* Cp    = fw + 2098176;          // 64*4096
  float* X     = fw + 2360320;          // M*1024  [hr2|hi2]
  float* y     = fw + 19137536;         // M*512
  float* qkv   = fw + 27526144;         // M*1536
  float* L     = fw + 52691968;         // M*512
  float* retr  = X;                     // alias: X dead after GEMM1

  prep_wcat<<<2048,256,0,stream>>>(ipWr, ipWi, WcatT);
  prep_qkvT<<<3072,256,0,stream>>>(Wqkv, WqkvT);
  prep_woT<<<2048,256,0,stream>>>(opWr, opWi, WoT);
  prep_misc<<<1,512,0,stream>>>(ipbr, ipbi, la, bc, alph, pw);

  scan_h<<<16,256,0,stream>>>(w, b, X);

  gemm_f32<<<dim3(4,128),256,0,stream>>>(X, WcatT, y, y, 512, 1024, 0);
  ln_kernel<<<4096,256,0,stream>>>(y, bc, lng, lnb);
  gemm_f32<<<dim3(12,128),256,0,stream>>>(y, WqkvT, qkv, qkv, 1536, 512, 0);

  vscan_local<<<1024,256,0,stream>>>(qkv, alph, L, E);
  vscan_carry<<<16,256,0,stream>>>(E, alph, pw, Cp);
  retr_kernel<<<32768,256,0,stream>>>(qkv, L, Cp, pw, retr);

  gemm_f32<<<dim3(8,128),256,0,stream>>>(retr, WoT, out0, out1, 1024, 512, 1);
}

// Round 2
// 514.279 us; speedup vs baseline: 2.6984x; 2.6984x over previous
//
#include <hip/hip_runtime.h>
#include <math.h>

#define BB 8
#define SS 2048
#define DD 512
#define HH 8
#define MM (BB*SS)   // 16384

typedef unsigned short u16;
typedef float f32x4 __attribute__((ext_vector_type(4)));
typedef short s16x8 __attribute__((ext_vector_type(8)));

__device__ __forceinline__ u16 f2bf(float x){
  union { float f; unsigned u; } c; c.f = x;
  unsigned r = c.u + 0x7FFF + ((c.u >> 16) & 1);
  return (u16)(r >> 16);
}

// ---------------- prep kernels ----------------
__global__ void prep_w1(const float* __restrict__ Wr, const float* __restrict__ Wi,
                        u16* __restrict__ W1){
  int id = blockIdx.x*256 + threadIdx.x;            // 512*1024: W1[n][k]
  if (id >= 512*1024) return;
  int n = id >> 10, k = id & 1023;
  float v = (k < 512) ? (Wr[n*512+k] + Wi[n*512+k])
                      : (Wr[n*512+(k-512)] - Wi[n*512+(k-512)]);
  W1[id] = f2bf(v);
}
__global__ void prep_wq(const float* __restrict__ Wq, u16* __restrict__ O){
  int id = blockIdx.x*256 + threadIdx.x;            // 1536*512, already [N][K]
  if (id >= 1536*512) return;
  O[id] = f2bf(Wq[id]);
}
__global__ void prep_w3(const float* __restrict__ Wor, const float* __restrict__ Woi,
                        u16* __restrict__ W3){
  int id = blockIdx.x*256 + threadIdx.x;            // 1024*512: W3[n][k]
  if (id >= 1024*512) return;
  int n = id >> 9, k = id & 511;
  W3[id] = f2bf((n < 512) ? Wor[n*512+k] : Woi[(n-512)*512+k]);
}
__global__ void prep_misc(const float* __restrict__ br, const float* __restrict__ bi,
                          const float* __restrict__ la, float* __restrict__ bc,
                          float* __restrict__ alph, float* __restrict__ pw){
  int t = threadIdx.x;
  if (t < 512) bc[t] = br[t] + bi[t];
  if (t < 8){
    float a = 1.0f/(1.0f + expf(-la[t]));
    alph[t] = a;
    float om = 1.0f - a;
    float p = 1.0f;
    pw[t*33] = 1.0f;
    for (int i=1;i<33;i++){ p *= om; pw[t*33+i] = p; }
  }
}

// ---------------- phase 1: elementwise h-recurrence ----------------
// X[M][1024] bf16: cols 0..511 = hr2 = cos(theta), cols 512..1023 = hi2 = sin(theta)
__global__ __launch_bounds__(256) void scan_h(const float* __restrict__ w,
                                              const float* __restrict__ bb,
                                              u16* __restrict__ X){
  const int gid = blockIdx.x*256 + threadIdx.x;   // 4096 = B*D
  const int b = gid >> 9;
  const int d = gid & 511;
  const float PHI_F    = 1.61803398874989484820f;
  const float TWO_PI_F = 6.28318530717958647693f;
  const float* wp = w  + (size_t)b*SS*DD + d;
  const float* bp = bb + (size_t)b*SS*DD + d;
  u16* xp = X + (size_t)b*SS*1024 + d;
  float hr = 0.f, hi = 0.f;
  const int U = 16;
  float wv[U], bv[U], wn[U], bn[U];
  #pragma unroll
  for (int i=0;i<U;i++){ wv[i] = wp[(size_t)i*DD]; bv[i] = bp[(size_t)i*DD]; }
  for (int c = 0; c < SS/U; ++c){
    if (c+1 < SS/U){
      const size_t base = (size_t)(c+1)*U;
      #pragma unroll
      for (int i=0;i<U;i++){ wn[i] = wp[(base+i)*DD]; bn[i] = bp[(base+i)*DD]; }
    }
    #pragma unroll
    for (int i=0;i<U;i++){
      int t = c*U + i;
      float tphi = fmodf((float)t * PHI_F, TWO_PI_F);
      float rwl = 1.0f/(1.0f + fabsf(wv[i]));
      float theta = (hr + hi)*rwl + 2.0f*bv[i] + 2.0f*tphi;
      float sn = __sinf(theta);
      float cs = __cosf(theta);
      hr = cs; hi = sn;
      u16* row = xp + (size_t)t*1024;
      row[0]   = f2bf(cs);
      row[512] = f2bf(sn);
    }
    #pragma unroll
    for (int i=0;i<U;i++){ wv[i]=wn[i]; bv[i]=bn[i]; }
  }
}

// ---------------- bf16 MFMA GEMM: C[M x N] = A[M x K] @ W[N x K]^T ----------------
// 128x128 tile, BK=32, 256 threads = 4 waves (2x2), 4x4 16x16x32 MFMA frags/wave.
// EPI==0: store C0 (row stride N). EPI==1: col<512 -> C0 else C1 (row stride 512).
__global__ __launch_bounds__(256) void gemm_bf16(const u16* __restrict__ A,
                                                 const u16* __restrict__ W,
                                                 float* __restrict__ C0,
                                                 float* __restrict__ C1,
                                                 int N, int K, int EPI){
  __shared__ __align__(16) u16 As[128*32];
  __shared__ __align__(16) u16 Bs[128*32];
  const int tid  = threadIdx.x;
  const int m0   = blockIdx.y * 128;
  const int n0   = blockIdx.x * 128;
  const int wave = tid >> 6;
  const int lane = tid & 63;
  const int wr   = wave >> 1, wc = wave & 1;
  const int l15  = lane & 15;
  const int g    = lane >> 4;

  // staging: thread t loads rows (t>>2) and (t>>2)+64, k-group (t&3)
  const int srow = tid >> 2;
  const int scol = tid & 3;
  const u16* Ap0 = A + (size_t)(m0 + srow) * K + scol*8;
  const u16* Ap1 = Ap0 + (size_t)64 * K;
  const u16* Bp0 = W + (size_t)(n0 + srow) * K + scol*8;
  const u16* Bp1 = Bp0 + (size_t)64 * K;
  // XOR-swizzled LDS element offsets (same formula on write & read)
  const int sw0 = srow*32      + ((scol ^ ((srow>>1)&3))*8);
  const int sw1 = (srow+64)*32 + ((scol ^ (((srow+64)>>1)&3))*8);

  f32x4 acc[4][4];
  #pragma unroll
  for (int i=0;i<4;i++)
    #pragma unroll
    for (int j=0;j<4;j++) acc[i][j] = (f32x4){0.f,0.f,0.f,0.f};

  s16x8 ra0 = *(const s16x8*)(Ap0);
  s16x8 ra1 = *(const s16x8*)(Ap1);
  s16x8 rb0 = *(const s16x8*)(Bp0);
  s16x8 rb1 = *(const s16x8*)(Bp1);

  for (int k0 = 0; k0 < K; k0 += 32){
    __syncthreads();
    *(s16x8*)&As[sw0] = ra0;
    *(s16x8*)&As[sw1] = ra1;
    *(s16x8*)&Bs[sw0] = rb0;
    *(s16x8*)&Bs[sw1] = rb1;
    __syncthreads();
    if (k0 + 32 < K){
      ra0 = *(const s16x8*)(Ap0 + k0 + 32);
      ra1 = *(const s16x8*)(Ap1 + k0 + 32);
      rb0 = *(const s16x8*)(Bp0 + k0 + 32);
      rb1 = *(const s16x8*)(Bp1 + k0 + 32);
    }
    s16x8 af[4], bf[4];
    #pragma unroll
    for (int s=0;s<4;s++){
      int rA = wr*64 + s*16 + l15;
      af[s] = *(const s16x8*)&As[rA*32 + ((g ^ ((rA>>1)&3))*8)];
      int rB = wc*64 + s*16 + l15;
      bf[s] = *(const s16x8*)&Bs[rB*32 + ((g ^ ((rB>>1)&3))*8)];
    }
    #pragma unroll
    for (int mi=0;mi<4;mi++)
      #pragma unroll
      for (int ni=0;ni<4;ni++)
        acc[mi][ni] = __builtin_amdgcn_mfma_f32_16x16x32_bf16(af[mi], bf[ni], acc[mi][ni], 0, 0, 0);
  }

  #pragma unroll
  for (int mi=0;mi<4;mi++){
    #pragma unroll
    for (int j=0;j<4;j++){
      int r = m0 + wr*64 + mi*16 + g*4 + j;
      #pragma unroll
      for (int ni=0;ni<4;ni++){
        int col = n0 + wc*64 + ni*16 + l15;
        float v = acc[mi][ni][j];
        if (EPI == 0){
          C0[(size_t)r*N + col] = v;
        } else {
          if (col < 512) C0[(size_t)r*512 + col]       = v;
          else           C1[(size_t)r*512 + (col-512)] = v;
        }
      }
    }
  }
}

// ---------------- LayerNorm: xc = LN(y + bc)*g + b  (fp32 in, bf16 out) ----------------
__global__ __launch_bounds__(256) void ln_kernel(const float* __restrict__ y,
                                                 const float* __restrict__ bc,
                                                 const float* __restrict__ g,
                                                 const float* __restrict__ bb,
                                                 u16* __restrict__ xc){
  const int row  = blockIdx.x*4 + (threadIdx.x >> 6);
  const int lane = threadIdx.x & 63;
  const float* yr = y + (size_t)row*512;
  float4 v0 = ((const float4*)yr)[lane];
  float4 v1 = ((const float4*)yr)[lane+64];
  float4 c0 = ((const float4*)bc)[lane];
  float4 c1 = ((const float4*)bc)[lane+64];
  v0.x+=c0.x; v0.y+=c0.y; v0.z+=c0.z; v0.w+=c0.w;
  v1.x+=c1.x; v1.y+=c1.y; v1.z+=c1.z; v1.w+=c1.w;
  float s  = v0.x+v0.y+v0.z+v0.w + v1.x+v1.y+v1.z+v1.w;
  float s2 = v0.x*v0.x+v0.y*v0.y+v0.z*v0.z+v0.w*v0.w
           + v1.x*v1.x+v1.y*v1.y+v1.z*v1.z+v1.w*v1.w;
  #pragma unroll
  for (int off=32; off>0; off>>=1){ s += __shfl_xor(s, off); s2 += __shfl_xor(s2, off); }
  float mean = s * (1.0f/512.0f);
  float var  = s2 * (1.0f/512.0f) - mean*mean;
  float rstd = rsqrtf(var + 1e-5f);
  float4 g0 = ((const float4*)g)[lane],  g1 = ((const float4*)g)[lane+64];
  float4 b0 = ((const float4*)bb)[lane], b1 = ((const float4*)bb)[lane+64];
  ushort4 o0, o1;
  o0.x = f2bf((v0.x-mean)*rstd*g0.x + b0.x);
  o0.y = f2bf((v0.y-mean)*rstd*g0.y + b0.y);
  o0.z = f2bf((v0.z-mean)*rstd*g0.z + b0.z);
  o0.w = f2bf((v0.w-mean)*rstd*g0.w + b0.w);
  o1.x = f2bf((v1.x-mean)*rstd*g1.x + b1.x);
  o1.y = f2bf((v1.y-mean)*rstd*g1.y + b1.y);
  o1.z = f2bf((v1.z-mean)*rstd*g1.z + b1.z);
  o1.w = f2bf((v1.w-mean)*rstd*g1.w + b1.w);
  ushort4* xr = (ushort4*)(xc + (size_t)row*512);
  xr[lane]    = o0;
  xr[lane+64] = o1;
}

// ---------------- vs EMA: chunked parallel scan ----------------
__global__ __launch_bounds__(256) void vscan_local(const float* __restrict__ qkv,
                                                   const float* __restrict__ alph,
                                                   float* __restrict__ L,
                                                   float* __restrict__ E){
  const int gid = blockIdx.x*256 + threadIdx.x;   // 64 chunks * 4096 elements
  const int c = gid >> 12;
  const int e = gid & 4095;
  const int b = e >> 9, d = e & 511;
  const float a  = alph[d >> 6];
  const float om = 1.0f - a;
  const int t0 = c*32;
  const float* vp = qkv + ((size_t)(b*SS + t0))*1536 + 1024 + d;
  float* lp = L + ((size_t)(b*SS + t0))*512 + d;
  float vs = 0.f;
  #pragma unroll 4
  for (int i=0;i<32;i++){
    float v = vp[(size_t)i*1536];
    vs = a*v + om*vs;
    lp[(size_t)i*512] = vs;
  }
  E[c*4096 + e] = vs;
}
__global__ void vscan_carry(const float* __restrict__ E, const float* __restrict__ alph,
                            const float* __restrict__ pw, float* __restrict__ Cp){
  const int gid = blockIdx.x*blockDim.x + threadIdx.x;  // 4096
  if (gid >= 4096) return;
  const int d = gid & 511;
  const float P = pw[(d>>6)*33 + 32];   // (1-a)^32
  float carry = 0.f;
  for (int c=0;c<64;c++){
    Cp[c*4096 + gid] = carry;
    carry = E[c*4096 + gid] + P*carry;
  }
}
// gate + vs fix-up + retr (bf16 out)
__global__ __launch_bounds__(256) void retr_kernel(const float* __restrict__ qkv,
                                                   const float* __restrict__ L,
                                                   const float* __restrict__ Cp,
                                                   const float* __restrict__ pw,
                                                   u16* __restrict__ retr){
  const int gid = blockIdx.x*256 + threadIdx.x;   // M*512
  const int r = gid >> 9, d = gid & 511;
  const int b = r >> 11, t = r & 2047;
  float q  = qkv[(size_t)r*1536 + d];
  float kk = qkv[(size_t)r*1536 + 512 + d];
  float qk = q*kk;
  #pragma unroll
  for (int off=32; off>0; off>>=1) qk += __shfl_xor(qk, off);
  float gate = 1.0f/(1.0f + __expf(-qk*0.125f));
  int h = d >> 6, c = t >> 5, i = t & 31;
  float vs = L[gid] + pw[h*33 + i + 1] * Cp[c*4096 + b*512 + d];
  retr[gid] = f2bf(gate * vs);
}

extern "C" void kernel_launch(void* const* d_in, const int* in_sizes, int n_in,
                              void* d_out, int out_size, void* d_ws, size_t ws_size,
                              hipStream_t stream) {
  const float* w    = (const float*)d_in[0];
  const float* b    = (const float*)d_in[1];
  const float* ipWr = (const float*)d_in[2];
  const float* ipWi = (const float*)d_in[3];
  const float* ipbr = (const float*)d_in[4];
  const float* ipbi = (const float*)d_in[5];
  const float* lng  = (const float*)d_in[6];
  const float* lnb  = (const float*)d_in[7];
  const float* Wqkv = (const float*)d_in[8];
  const float* la   = (const float*)d_in[9];
  const float* opWr = (const float*)d_in[10];
  const float* opWi = (const float*)d_in[11];
  float* out0 = (float*)d_out;                    // (B,S,D) real part
  float* out1 = out0 + (size_t)MM*DD;             // imag part

  char* base = (char*)d_ws;
  u16*   W1   = (u16*)  (base + 0);               // 512x1024 bf16
  u16*   Wq   = (u16*)  (base + 1048576);         // 1536x512 bf16
  u16*   W3   = (u16*)  (base + 2621440);         // 1024x512 bf16
  float* bc   = (float*)(base + 3670016);         // 512
  float* alph = (float*)(base + 3672064);         // 8
  float* pw   = (float*)(base + 3672096);         // 8*33
  float* E    = (float*)(base + 3673344);         // 64*4096
  float* Cp   = (float*)(base + 4721920);         // 64*4096
  u16*   X    = (u16*)  (base + 5770496);         // M*1024 bf16 [hr2|hi2]
  float* y    = (float*)(base + 39324928);        // M*512 f32
  u16*   xc   = (u16*)  (base + 72879360);        // M*512 bf16
  float* qkv  = (float*)(base + 89656576);        // M*1536 f32
  float* L    = (float*)(base + 190319872);       // M*512 f32
  u16*   retr = X;                                // alias: X dead after GEMM1

  prep_w1 <<<2048,256,0,stream>>>(ipWr, ipWi, W1);
  prep_wq <<<3072,256,0,stream>>>(Wqkv, Wq);
  prep_w3 <<<2048,256,0,stream>>>(opWr, opWi, W3);
  prep_misc<<<1,512,0,stream>>>(ipbr, ipbi, la, bc, alph, pw);

  scan_h<<<16,256,0,stream>>>(w, b, X);

  gemm_bf16<<<dim3(4,128),256,0,stream>>>(X, W1, y, y, 512, 1024, 0);
  ln_kernel<<<4096,256,0,stream>>>(y, bc, lng, lnb, xc);
  gemm_bf16<<<dim3(12,128),256,0,stream>>>(xc, Wq, qkv, qkv, 1536, 512, 0);

  vscan_local<<<1024,256,0,stream>>>(qkv, alph, L, E);
  vscan_carry<<<16,256,0,stream>>>(E, alph, pw, Cp);
  retr_kernel<<<32768,256,0,stream>>>(qkv, L, Cp, pw, retr);

  gemm_bf16<<<dim3(8,128),256,0,stream>>>(retr, W3, out0, out1, 1024, 512, 1);
}

// Round 3
// 224.012 us; speedup vs baseline: 6.1948x; 2.2958x over previous
//
#include <hip/hip_runtime.h>
#include <math.h>

#define BB 8
#define SS 2048
#define DD 512
#define HH 8
#define MM (BB*SS)   // 16384

// scan_h chunking
#define CHK 32    // chunks over t
#define CL  64    // stored steps per chunk (CHK*CL == SS)
#define CW  64    // warm-up steps (contraction ~e^-0.87/step)

typedef unsigned short u16;
typedef float f32x4 __attribute__((ext_vector_type(4)));
typedef short s16x8 __attribute__((ext_vector_type(8)));

__device__ __forceinline__ u16 f2bf(float x){
  union { float f; unsigned u; } c; c.f = x;
  unsigned r = c.u + 0x7FFF + ((c.u >> 16) & 1);
  return (u16)(r >> 16);
}

// ---------------- prep kernels ----------------
__global__ void prep_w1(const float* __restrict__ Wr, const float* __restrict__ Wi,
                        u16* __restrict__ W1){
  int id = blockIdx.x*256 + threadIdx.x;            // 512*1024: W1[n][k]
  if (id >= 512*1024) return;
  int n = id >> 10, k = id & 1023;
  float v = (k < 512) ? (Wr[n*512+k] + Wi[n*512+k])
                      : (Wr[n*512+(k-512)] - Wi[n*512+(k-512)]);
  W1[id] = f2bf(v);
}
__global__ void prep_wq(const float* __restrict__ Wq, u16* __restrict__ O){
  int id = blockIdx.x*256 + threadIdx.x;            // 1536*512, already [N][K]
  if (id >= 1536*512) return;
  O[id] = f2bf(Wq[id]);
}
__global__ void prep_w3(const float* __restrict__ Wor, const float* __restrict__ Woi,
                        u16* __restrict__ W3){
  int id = blockIdx.x*256 + threadIdx.x;            // 1024*512: W3[n][k]
  if (id >= 1024*512) return;
  int n = id >> 9, k = id & 511;
  W3[id] = f2bf((n < 512) ? Wor[n*512+k] : Woi[(n-512)*512+k]);
}
__global__ void prep_misc(const float* __restrict__ br, const float* __restrict__ bi,
                          const float* __restrict__ la, float* __restrict__ bc,
                          float* __restrict__ alph, float* __restrict__ pw){
  int t = threadIdx.x;
  if (t < 512) bc[t] = br[t] + bi[t];
  if (t < 8){
    float a = 1.0f/(1.0f + expf(-la[t]));
    alph[t] = a;
    float om = 1.0f - a;
    float p = 1.0f;
    pw[t*33] = 1.0f;
    for (int i=1;i<33;i++){ p *= om; pw[t*33+i] = p; }
  }
}

// ---------------- phase 1: h-recurrence, chunked restart ----------------
// X[M][1024] bf16: cols 0..511 = hr2 = cos(theta), cols 512..1023 = hi2 = sin(theta)
// theta_t = (hr+hi)/(1+|w_t|) + 2*b_t + 2*(t*PHI mod 2pi)
__global__ __launch_bounds__(256) void scan_h(const float* __restrict__ w,
                                              const float* __restrict__ bb,
                                              u16* __restrict__ X){
  const int e = blockIdx.x*256 + threadIdx.x;   // 0..4095 = B*D
  const int c = blockIdx.y;                     // chunk
  const int b = e >> 9;
  const int d = e & 511;
  const float PHI_F    = 1.61803398874989484820f;
  const float TWO_PI_F = 6.28318530717958647693f;
  const int tstart = c*CL;
  int t0 = tstart - CW; if (t0 < 0) t0 = 0;
  const int nw = tstart - t0;

  const float* wp = w  + ((size_t)b*SS + t0)*DD + d;
  const float* bp = bb + ((size_t)b*SS + t0)*DD + d;
  float hr = 0.f, hi = 0.f;

  #pragma unroll 8
  for (int i=0;i<nw;i++){
    float wv = wp[(size_t)i*DD];
    float bv = bp[(size_t)i*DD];
    float t  = (float)(t0 + i);
    float tphi = fmodf(t * PHI_F, TWO_PI_F);
    float rwl  = 1.0f/(1.0f + fabsf(wv));
    float theta = (hr + hi)*rwl + 2.0f*bv + 2.0f*tphi;
    hi = __sinf(theta);
    hr = __cosf(theta);
  }
  const float* wq = wp + (size_t)nw*DD;
  const float* bq = bp + (size_t)nw*DD;
  u16* xp = X + ((size_t)(b*SS + tstart))*1024 + d;
  #pragma unroll 8
  for (int i=0;i<CL;i++){
    float wv = wq[(size_t)i*DD];
    float bv = bq[(size_t)i*DD];
    float t  = (float)(tstart + i);
    float tphi = fmodf(t * PHI_F, TWO_PI_F);
    float rwl  = 1.0f/(1.0f + fabsf(wv));
    float theta = (hr + hi)*rwl + 2.0f*bv + 2.0f*tphi;
    hi = __sinf(theta);
    hr = __cosf(theta);
    u16* row = xp + (size_t)i*1024;
    row[0]   = f2bf(hr);
    row[512] = f2bf(hi);
  }
}

// ---------------- bf16 MFMA GEMM: C[M x N] = A[M x K] @ W[N x K]^T ----------------
// 128x128 tile, BK=32, 256 threads = 4 waves (2x2), 4x4 16x16x32 MFMA frags/wave.
// EPI==0: store C0 (row stride N). EPI==1: col<512 -> C0 else C1 (row stride 512).
__global__ __launch_bounds__(256) void gemm_bf16(const u16* __restrict__ A,
                                                 const u16* __restrict__ W,
                                                 float* __restrict__ C0,
                                                 float* __restrict__ C1,
                                                 int N, int K, int EPI){
  __shared__ __align__(16) u16 As[128*32];
  __shared__ __align__(16) u16 Bs[128*32];
  const int tid  = threadIdx.x;
  const int m0   = blockIdx.y * 128;
  const int n0   = blockIdx.x * 128;
  const int wave = tid >> 6;
  const int lane = tid & 63;
  const int wr   = wave >> 1, wc = wave & 1;
  const int l15  = lane & 15;
  const int g    = lane >> 4;

  const int srow = tid >> 2;
  const int scol = tid & 3;
  const u16* Ap0 = A + (size_t)(m0 + srow) * K + scol*8;
  const u16* Ap1 = Ap0 + (size_t)64 * K;
  const u16* Bp0 = W + (size_t)(n0 + srow) * K + scol*8;
  const u16* Bp1 = Bp0 + (size_t)64 * K;
  const int sw0 = srow*32      + ((scol ^ ((srow>>1)&3))*8);
  const int sw1 = (srow+64)*32 + ((scol ^ (((srow+64)>>1)&3))*8);

  f32x4 acc[4][4];
  #pragma unroll
  for (int i=0;i<4;i++)
    #pragma unroll
    for (int j=0;j<4;j++) acc[i][j] = (f32x4){0.f,0.f,0.f,0.f};

  s16x8 ra0 = *(const s16x8*)(Ap0);
  s16x8 ra1 = *(const s16x8*)(Ap1);
  s16x8 rb0 = *(const s16x8*)(Bp0);
  s16x8 rb1 = *(const s16x8*)(Bp1);

  for (int k0 = 0; k0 < K; k0 += 32){
    __syncthreads();
    *(s16x8*)&As[sw0] = ra0;
    *(s16x8*)&As[sw1] = ra1;
    *(s16x8*)&Bs[sw0] = rb0;
    *(s16x8*)&Bs[sw1] = rb1;
    __syncthreads();
    if (k0 + 32 < K){
      ra0 = *(const s16x8*)(Ap0 + k0 + 32);
      ra1 = *(const s16x8*)(Ap1 + k0 + 32);
      rb0 = *(const s16x8*)(Bp0 + k0 + 32);
      rb1 = *(const s16x8*)(Bp1 + k0 + 32);
    }
    s16x8 af[4], bf[4];
    #pragma unroll
    for (int s=0;s<4;s++){
      int rA = wr*64 + s*16 + l15;
      af[s] = *(const s16x8*)&As[rA*32 + ((g ^ ((rA>>1)&3))*8)];
      int rB = wc*64 + s*16 + l15;
      bf[s] = *(const s16x8*)&Bs[rB*32 + ((g ^ ((rB>>1)&3))*8)];
    }
    #pragma unroll
    for (int mi=0;mi<4;mi++)
      #pragma unroll
      for (int ni=0;ni<4;ni++)
        acc[mi][ni] = __builtin_amdgcn_mfma_f32_16x16x32_bf16(af[mi], bf[ni], acc[mi][ni], 0, 0, 0);
  }

  #pragma unroll
  for (int mi=0;mi<4;mi++){
    #pragma unroll
    for (int j=0;j<4;j++){
      int r = m0 + wr*64 + mi*16 + g*4 + j;
      #pragma unroll
      for (int ni=0;ni<4;ni++){
        int col = n0 + wc*64 + ni*16 + l15;
        float v = acc[mi][ni][j];
        if (EPI == 0){
          C0[(size_t)r*N + col] = v;
        } else {
          if (col < 512) C0[(size_t)r*512 + col]       = v;
          else           C1[(size_t)r*512 + (col-512)] = v;
        }
      }
    }
  }
}

// ---------------- LayerNorm: xc = LN(y + bc)*g + b  (fp32 in, bf16 out) ----------------
__global__ __launch_bounds__(256) void ln_kernel(const float* __restrict__ y,
                                                 const float* __restrict__ bc,
                                                 const float* __restrict__ g,
                                                 const float* __restrict__ bb,
                                                 u16* __restrict__ xc){
  const int row  = blockIdx.x*4 + (threadIdx.x >> 6);
  const int lane = threadIdx.x & 63;
  const float* yr = y + (size_t)row*512;
  float4 v0 = ((const float4*)yr)[lane];
  float4 v1 = ((const float4*)yr)[lane+64];
  float4 c0 = ((const float4*)bc)[lane];
  float4 c1 = ((const float4*)bc)[lane+64];
  v0.x+=c0.x; v0.y+=c0.y; v0.z+=c0.z; v0.w+=c0.w;
  v1.x+=c1.x; v1.y+=c1.y; v1.z+=c1.z; v1.w+=c1.w;
  float s  = v0.x+v0.y+v0.z+v0.w + v1.x+v1.y+v1.z+v1.w;
  float s2 = v0.x*v0.x+v0.y*v0.y+v0.z*v0.z+v0.w*v0.w
           + v1.x*v1.x+v1.y*v1.y+v1.z*v1.z+v1.w*v1.w;
  #pragma unroll
  for (int off=32; off>0; off>>=1){ s += __shfl_xor(s, off); s2 += __shfl_xor(s2, off); }
  float mean = s * (1.0f/512.0f);
  float var  = s2 * (1.0f/512.0f) - mean*mean;
  float rstd = rsqrtf(var + 1e-5f);
  float4 g0 = ((const float4*)g)[lane],  g1 = ((const float4*)g)[lane+64];
  float4 b0 = ((const float4*)bb)[lane], b1 = ((const float4*)bb)[lane+64];
  ushort4 o0, o1;
  o0.x = f2bf((v0.x-mean)*rstd*g0.x + b0.x);
  o0.y = f2bf((v0.y-mean)*rstd*g0.y + b0.y);
  o0.z = f2bf((v0.z-mean)*rstd*g0.z + b0.z);
  o0.w = f2bf((v0.w-mean)*rstd*g0.w + b0.w);
  o1.x = f2bf((v1.x-mean)*rstd*g1.x + b1.x);
  o1.y = f2bf((v1.y-mean)*rstd*g1.y + b1.y);
  o1.z = f2bf((v1.z-mean)*rstd*g1.z + b1.z);
  o1.w = f2bf((v1.w-mean)*rstd*g1.w + b1.w);
  ushort4* xr = (ushort4*)(xc + (size_t)row*512);
  xr[lane]    = o0;
  xr[lane+64] = o1;
}

// ---------------- vs EMA: chunked parallel scan ----------------
__global__ __launch_bounds__(256) void vscan_local(const float* __restrict__ qkv,
                                                   const float* __restrict__ alph,
                                                   float* __restrict__ L,
                                                   float* __restrict__ E){
  const int gid = blockIdx.x*256 + threadIdx.x;   // 64 chunks * 4096 elements
  const int c = gid >> 12;
  const int e = gid & 4095;
  const int b = e >> 9, d = e & 511;
  const float a  = alph[d >> 6];
  const float om = 1.0f - a;
  const int t0 = c*32;
  const float* vp = qkv + ((size_t)(b*SS + t0))*1536 + 1024 + d;
  float* lp = L + ((size_t)(b*SS + t0))*512 + d;
  float vs = 0.f;
  #pragma unroll 4
  for (int i=0;i<32;i++){
    float v = vp[(size_t)i*1536];
    vs = a*v + om*vs;
    lp[(size_t)i*512] = vs;
  }
  E[c*4096 + e] = vs;
}
__global__ void vscan_carry(const float* __restrict__ E, const float* __restrict__ alph,
                            const float* __restrict__ pw, float* __restrict__ Cp){
  const int gid = blockIdx.x*blockDim.x + threadIdx.x;  // 4096
  if (gid >= 4096) return;
  const int d = gid & 511;
  const float P = pw[(d>>6)*33 + 32];   // (1-a)^32
  float carry = 0.f;
  for (int c=0;c<64;c++){
    Cp[c*4096 + gid] = carry;
    carry = E[c*4096 + gid] + P*carry;
  }
}
// gate + vs fix-up + retr (bf16 out)
__global__ __launch_bounds__(256) void retr_kernel(const float* __restrict__ qkv,
                                                   const float* __restrict__ L,
                                                   const float* __restrict__ Cp,
                                                   const float* __restrict__ pw,
                                                   u16* __restrict__ retr){
  const int gid = blockIdx.x*256 + threadIdx.x;   // M*512
  const int r = gid >> 9, d = gid & 511;
  const int b = r >> 11, t = r & 2047;
  float q  = qkv[(size_t)r*1536 + d];
  float kk = qkv[(size_t)r*1536 + 512 + d];
  float qk = q*kk;
  #pragma unroll
  for (int off=32; off>0; off>>=1) qk += __shfl_xor(qk, off);
  float gate = 1.0f/(1.0f + __expf(-qk*0.125f));
  int h = d >> 6, c = t >> 5, i = t & 31;
  float vs = L[gid] + pw[h*33 + i + 1] * Cp[c*4096 + b*512 + d];
  retr[gid] = f2bf(gate * vs);
}

extern "C" void kernel_launch(void* const* d_in, const int* in_sizes, int n_in,
                              void* d_out, int out_size, void* d_ws, size_t ws_size,
                              hipStream_t stream) {
  const float* w    = (const float*)d_in[0];
  const float* b    = (const float*)d_in[1];
  const float* ipWr = (const float*)d_in[2];
  const float* ipWi = (const float*)d_in[3];
  const float* ipbr = (const float*)d_in[4];
  const float* ipbi = (const float*)d_in[5];
  const float* lng  = (const float*)d_in[6];
  const float* lnb  = (const float*)d_in[7];
  const float* Wqkv = (const float*)d_in[8];
  const float* la   = (const float*)d_in[9];
  const float* opWr = (const float*)d_in[10];
  const float* opWi = (const float*)d_in[11];
  float* out0 = (float*)d_out;                    // (B,S,D) real part
  float* out1 = out0 + (size_t)MM*DD;             // imag part

  char* base = (char*)d_ws;
  u16*   W1   = (u16*)  (base + 0);               // 512x1024 bf16
  u16*   Wq   = (u16*)  (base + 1048576);         // 1536x512 bf16
  u16*   W3   = (u16*)  (base + 2621440);         // 1024x512 bf16
  float* bc   = (float*)(base + 3670016);         // 512
  float* alph = (float*)(base + 3672064);         // 8
  float* pw   = (float*)(base + 3672096);         // 8*33
  float* E    = (float*)(base + 3673344);         // 64*4096
  float* Cp   = (float*)(base + 4721920);         // 64*4096
  u16*   X    = (u16*)  (base + 5770496);         // M*1024 bf16 [hr2|hi2]
  float* y    = (float*)(base + 39324928);        // M*512 f32
  u16*   xc   = (u16*)  (base + 72879360);        // M*512 bf16
  float* qkv  = (float*)(base + 89656576);        // M*1536 f32
  float* L    = (float*)(base + 190319872);       // M*512 f32
  u16*   retr = X;                                // alias: X dead after GEMM1

  prep_w1 <<<2048,256,0,stream>>>(ipWr, ipWi, W1);
  prep_wq <<<3072,256,0,stream>>>(Wqkv, Wq);
  prep_w3 <<<2048,256,0,stream>>>(opWr, opWi, W3);
  prep_misc<<<1,512,0,stream>>>(ipbr, ipbi, la, bc, alph, pw);

  scan_h<<<dim3(16,CHK),256,0,stream>>>(w, b, X);

  gemm_bf16<<<dim3(4,128),256,0,stream>>>(X, W1, y, y, 512, 1024, 0);
  ln_kernel<<<4096,256,0,stream>>>(y, bc, lng, lnb, xc);
  gemm_bf16<<<dim3(12,128),256,0,stream>>>(xc, Wq, qkv, qkv, 1536, 512, 0);

  vscan_local<<<1024,256,0,stream>>>(qkv, alph, L, E);
  vscan_carry<<<16,256,0,stream>>>(E, alph, pw, Cp);
  retr_kernel<<<32768,256,0,stream>>>(qkv, L, Cp, pw, retr);

  gemm_bf16<<<dim3(8,128),256,0,stream>>>(retr, W3, out0, out1, 1024, 512, 1);
}